// Round 1
// baseline (24080.547 us; speedup 1.0000x reference)
//
#include <hip/hip_runtime.h>
#include <math.h>

#define Bz 64
#define Tz 32
#define Ez 256
#define Uz 512
#define NITER 31
#define G4 2048

__device__ __forceinline__ float sigf(float x) { return 1.f / (1.f + expf(-x)); }

__device__ __forceinline__ void bg_barrier(unsigned* ctr, unsigned target) {
  __syncthreads();
  if (threadIdx.x == 0) {
    __threadfence();
    __hip_atomic_fetch_add(ctr, 1u, __ATOMIC_RELEASE, __HIP_MEMORY_SCOPE_AGENT);
    while (__hip_atomic_load(ctr, __ATOMIC_ACQUIRE, __HIP_MEMORY_SCOPE_AGENT) < target) {
      __builtin_amdgcn_s_sleep(1);
    }
  }
  __syncthreads();
}

// ---------------- generic f32 GEMM: C[M,N] = A[rows][K] @ B[K,N] (+bias) ----------------
// grid = (N/64, M/64), block = 256. All dims multiples of 64 (K mult of 16).
__global__ __launch_bounds__(256) void gemm_f32(
    const float* __restrict__ A, const int* __restrict__ Arows, int lda,
    const float* __restrict__ Bm, int ldb, const float* __restrict__ bias,
    float* __restrict__ C, int N, int K)
{
  __shared__ __align__(16) float As[16][68];
  __shared__ __align__(16) float Bs[16][68];
  const int tid = threadIdx.x;
  const int bm = blockIdx.y, bn = blockIdx.x;
  const int tx = tid & 15, ty = tid >> 4;
  float acc[4][4] = {{0.f}};
  const int sm = tid >> 2, sk = (tid & 3) * 4;
  const int arow = Arows ? Arows[bm * 64 + sm] : (bm * 64 + sm);
  const float* Ap = A + (size_t)arow * lda + sk;
  const int bk = tid >> 4, bn4 = (tid & 15) * 4;
  const float* Bp = Bm + (size_t)bk * ldb + bn * 64 + bn4;
  for (int kk = 0; kk < K; kk += 16) {
    float4 av = *(const float4*)(Ap + kk);
    float4 bv = *(const float4*)(Bp + (size_t)kk * ldb);
    As[sk + 0][sm] = av.x; As[sk + 1][sm] = av.y;
    As[sk + 2][sm] = av.z; As[sk + 3][sm] = av.w;
    *(float4*)&Bs[bk][bn4] = bv;
    __syncthreads();
#pragma unroll
    for (int kt = 0; kt < 16; ++kt) {
      float4 a = *(const float4*)&As[kt][ty * 4];
      float4 b = *(const float4*)&Bs[kt][tx * 4];
      acc[0][0] += a.x * b.x; acc[0][1] += a.x * b.y; acc[0][2] += a.x * b.z; acc[0][3] += a.x * b.w;
      acc[1][0] += a.y * b.x; acc[1][1] += a.y * b.y; acc[1][2] += a.y * b.z; acc[1][3] += a.y * b.w;
      acc[2][0] += a.z * b.x; acc[2][1] += a.z * b.y; acc[2][2] += a.z * b.z; acc[2][3] += a.z * b.w;
      acc[3][0] += a.w * b.x; acc[3][1] += a.w * b.y; acc[3][2] += a.w * b.z; acc[3][3] += a.w * b.w;
    }
    __syncthreads();
  }
  const int cm = bm * 64 + ty * 4, cn = bn * 64 + tx * 4;
  float bc0 = bias ? bias[cn + 0] : 0.f;
  float bc1 = bias ? bias[cn + 1] : 0.f;
  float bc2 = bias ? bias[cn + 2] : 0.f;
  float bc3 = bias ? bias[cn + 3] : 0.f;
#pragma unroll
  for (int i = 0; i < 4; ++i) {
    float4 o;
    o.x = acc[i][0] + bc0; o.y = acc[i][1] + bc1;
    o.z = acc[i][2] + bc2; o.w = acc[i][3] + bc3;
    *(float4*)&C[(size_t)(cm + i) * N + cn] = o;
  }
}

__global__ void init_kernel(const float* __restrict__ src_h, float* __restrict__ hb0,
                            unsigned* __restrict__ bar) {
  int i = blockIdx.x * blockDim.x + threadIdx.x;
  if (i < 128) bar[i] = 0u;
  for (int e = i; e < Bz * Uz; e += gridDim.x * blockDim.x) hb0[e] = src_h[e];
}

// ---------------- persistent decoder: 256 blocks x 512 threads, 1 block/CU ----------------
__global__ __launch_bounds__(512, 1) void decoder_persist(
    const float* __restrict__ Wr,        // [512][2048]
    const float* __restrict__ Wgen,      // [1280][512]
    const float* __restrict__ bgen,      // [512]
    const float* __restrict__ enc_c,     // [64][512]
    const float* __restrict__ embW,      // [512][2048]  emb[0:512]@Wk + b
    const float* __restrict__ xg0,       // [2048][2048] emb[target]@Wk + b
    const float* __restrict__ enc_part,  // [2048][512]
    const float* __restrict__ dec0,      // [2048][512]
    const float* __restrict__ decW,      // [512][512]
    float* __restrict__ hb,              // [2][64][512] double-buffered h
    float* __restrict__ h_pre,           // [64][512]
    float* __restrict__ hWb,             // [64][512]
    int*   __restrict__ idxbuf,          // [2048]
    unsigned* __restrict__ bar,          // [4*32]
    float* __restrict__ out)
{
  __shared__ __align__(16) float Wl[32][516];
  __shared__ __align__(16) float h_l[16][516];
  __shared__ float g_l[32][17];
  __shared__ float red_v[512];
  __shared__ int   red_i[512];

  const int tid = threadIdx.x;
  const int bid = blockIdx.x;
  const int bg = bid >> 6, ug = bid & 63;
  const int b0 = bg * 16, u0 = ug * 8;

  float* out_dec = out;
  float* out_pg  = out + (size_t)NITER * Bz * Tz * Uz;
  float* out_hs  = out + 2 * (size_t)NITER * Bz * Tz * Uz;
  float* out_cs  = out_hs + (size_t)NITER * Bz * Uz;

  unsigned* ctr = bar + bg * 32;
  unsigned bt_ = 0;

  // stage this block's Wr slice (8 u's x 4 gates, col-major over k) into LDS -- once
  for (int e = tid; e < 32 * 512; e += 512) {
    int k = e >> 5, jj = e & 31;
    Wl[jj][k] = Wr[(size_t)k * G4 + (jj >> 3) * Uz + u0 + (jj & 7)];
  }

  // compute-thread mapping: 512 threads -> (bl 0..15) x (j 0..31)
  const int lane = tid & 63, w = tid >> 6;
  const int bl = lane & 15, jq = lane >> 4;
  const int j  = w * 4 + jq;                    // j = gate*8 + uu
  const int gcol = (j >> 3) * Uz + u0 + (j & 7);
  const int rbase = (b0 + bl) * Tz;

  // pointwise mapping (tid < 128): (bl2 0..15) x (uu2 0..7)
  const int bl2 = tid >> 3, uu2 = tid & 7;
  float c_reg = 0.f;
  if (tid < 128) c_reg = enc_c[(b0 + bl2) * Uz + (u0 + uu2)];
  __syncthreads();

#pragma unroll 1
  for (int s = 0; s < NITER; ++s) {
    // prologue: save pre-update state (scan outputs h, c)
    if (tid < 128) {
      int b = b0 + bl2, u = u0 + uu2;
      float hp = hb[b * Uz + u];                       // parity 0 at iter start
      h_pre[b * Uz + u] = hp;
      out_hs[((size_t)s * Bz + b) * Uz + u] = hp;
      out_cs[((size_t)s * Bz + b) * Uz + u] = c_reg;
    }

    // ---- 32 LSTM steps ----
#pragma unroll 1
    for (int t = 0; t < Tz; ++t) {
      const float* hread = hb + (t & 1) * (Bz * Uz);
      float* hwrite = hb + ((t & 1) ^ 1) * (Bz * Uz);
      for (int q = tid; q < 2048; q += 512) {          // stage h slice [16][512]
        int sbl = q >> 7, k4 = q & 127;
        float4 v = *(const float4*)(hread + (b0 + sbl) * Uz + k4 * 4);
        *(float4*)&h_l[sbl][k4 * 4] = v;
      }
      float acc;                                       // xg gather (bias baked in)
      if (s == 0) acc = xg0[(size_t)(rbase + t) * G4 + gcol];
      else        acc = embW[(size_t)idxbuf[rbase + t] * G4 + gcol];
      __syncthreads();
#pragma unroll 4
      for (int k = 0; k < Uz; k += 4) {
        float4 hv = *(const float4*)&h_l[bl][k];
        float4 wv = *(const float4*)&Wl[j][k];
        acc += hv.x * wv.x; acc += hv.y * wv.y;
        acc += hv.z * wv.z; acc += hv.w * wv.w;
      }
      g_l[j][bl] = acc;
      __syncthreads();
      if (tid < 128) {
        float gi = g_l[ 0 + uu2][bl2];
        float gf = g_l[ 8 + uu2][bl2];
        float gc = g_l[16 + uu2][bl2];
        float go = g_l[24 + uu2][bl2];
        c_reg = sigf(gf) * c_reg + sigf(gi) * tanhf(gc);
        float hn = sigf(go) * tanhf(c_reg);
        int b = b0 + bl2, u = u0 + uu2;
        hwrite[b * Uz + u] = hn;
        out_dec[(((size_t)s * Bz + b) * Tz + t) * Uz + u] = hn;
      }
      bt_ += 64; bg_barrier(ctr, bt_);
    }

    // ---- hW = h_pre @ Wgen[512:1024]  (per bg: 16b x 512j) ----
    {
      int b = b0 + (ug >> 2), jg = ug & 3;
      if (tid < 128) {
        int jj = jg * 128 + tid;
        const float* hp = h_pre + b * Uz;
        const float* wg = Wgen + 512 * Uz + jj;
        float a2 = 0.f;
#pragma unroll 8
        for (int k = 0; k < Uz; ++k) a2 += hp[k] * wg[(size_t)k * Uz];
        hWb[b * Uz + jj] = a2;
      }
    }
    bt_ += 64; bg_barrier(ctr, bt_);

    // ---- p_gen = sigmoid(enc_part + hW + dec_part + bgen) ----
#pragma unroll 1
    for (int i = 0; i < 8; ++i) {
      int f = ug * 4096 + i * 512 + tid;
      int jj = f & 511, btl = f >> 9;
      int b = b0 + (btl >> 5), t = btl & 31;
      int rr = b * Tz + t;
      float dv;
      if (s == 0) dv = dec0[(size_t)rr * Uz + jj];
      else        dv = decW[(size_t)idxbuf[rr] * Uz + jj];
      float v = enc_part[(size_t)rr * Uz + jj] + hWb[b * Uz + jj] + dv + bgen[jj];
      out_pg[(((size_t)s * Bz + b) * Tz + t) * Uz + jj] = 1.f / (1.f + expf(-v));
    }
    bt_ += 64; bg_barrier(ctr, bt_);   // idx readers done before overwrite

    // ---- argmax over U (ties -> lowest index, matches jnp.argmax) ----
#pragma unroll 1
    for (int i = 0; i < 8; ++i) {
      int rl = ug * 8 + i;
      int b = b0 + (rl >> 5), t = rl & 31;
      const float* row = out_dec + (((size_t)s * Bz + b) * Tz + t) * Uz;
      red_v[tid] = row[tid];
      red_i[tid] = tid;
      __syncthreads();
      for (int off = 256; off > 0; off >>= 1) {
        if (tid < off) {
          float v2 = red_v[tid + off], v1 = red_v[tid];
          int i2 = red_i[tid + off], i1 = red_i[tid];
          if (v2 > v1 || (v2 == v1 && i2 < i1)) { red_v[tid] = v2; red_i[tid] = i2; }
        }
        __syncthreads();
      }
      if (tid == 0) idxbuf[b * Tz + t] = red_i[0];
      __syncthreads();
    }
    bt_ += 64; bg_barrier(ctr, bt_);   // idx visible for next iteration
  }
}

extern "C" void kernel_launch(void* const* d_in, const int* in_sizes, int n_in,
                              void* d_out, int out_size, void* d_ws, size_t ws_size,
                              hipStream_t stream) {
  const int*   target = (const int*)d_in[1];
  const float* enc    = (const float*)d_in[2];
  const float* enc_h  = (const float*)d_in[3];
  const float* enc_cp = (const float*)d_in[4];
  const float* emb    = (const float*)d_in[5];
  const float* Wk     = (const float*)d_in[6];
  const float* Wr     = (const float*)d_in[7];
  const float* bb     = (const float*)d_in[8];
  const float* Wgen   = (const float*)d_in[9];
  const float* bgen   = (const float*)d_in[10];
  float* out = (float*)d_out;

  float* ws = (float*)d_ws;
  float* hb       = ws;                         // 2*64*512      = 65536
  float* h_pre    = ws + 65536;                 // 64*512        = 32768
  float* hWb      = ws + 98304;                 // 64*512        = 32768
  float* embW     = ws + 131072;                // 512*2048      = 1048576
  float* xg0      = ws + 1179648;               // 2048*2048     = 4194304
  float* enc_part = ws + 5373952;               // 2048*512      = 1048576
  float* dec0     = ws + 6422528;               // 2048*512      = 1048576
  float* decW     = ws + 7471104;               // 512*512       = 262144
  int*   idxbuf   = (int*)(ws + 7733248);       // 2048
  unsigned* bar   = (unsigned*)(ws + 7735296);  // 128

  init_kernel<<<64, 512, 0, stream>>>(enc_h, hb, bar);
  // embW = emb[0:512] @ Wk + b           M=512  N=2048 K=256
  gemm_f32<<<dim3(32, 8), 256, 0, stream>>>(emb, nullptr, 256, Wk, 2048, bb, embW, 2048, 256);
  // xg0 = emb[target] @ Wk + b           M=2048 N=2048 K=256
  gemm_f32<<<dim3(32, 32), 256, 0, stream>>>(emb, target, 256, Wk, 2048, bb, xg0, 2048, 256);
  // enc_part = enc @ Wgen[0:512]         M=2048 N=512  K=512
  gemm_f32<<<dim3(8, 32), 256, 0, stream>>>(enc, nullptr, 512, Wgen, 512, nullptr, enc_part, 512, 512);
  // dec0 = emb[target] @ Wgen[1024:1280] M=2048 N=512  K=256
  gemm_f32<<<dim3(8, 32), 256, 0, stream>>>(emb, target, 256, Wgen + 1024 * 512, 512, nullptr, dec0, 512, 256);
  // decW = emb[0:512] @ Wgen[1024:1280]  M=512  N=512  K=256
  gemm_f32<<<dim3(8, 8), 256, 0, stream>>>(emb, nullptr, 256, Wgen + 1024 * 512, 512, nullptr, decW, 512, 256);

  decoder_persist<<<256, 512, 0, stream>>>(Wr, Wgen, bgen, enc_cp, embW, xg0,
      enc_part, dec0, decW, hb, h_pre, hWb, idxbuf, bar, out);
}

// Round 2
// 22120.236 us; speedup vs baseline: 1.0886x; 1.0886x over previous
//
#include <hip/hip_runtime.h>
#include <math.h>

#define Bz 64
#define Tz 32
#define Ez 256
#define Uz 512
#define NITER 31
#define G4 2048

__device__ __forceinline__ float sigf(float x) { return 1.f / (1.f + expf(-x)); }

// Distributed flag barrier for one bg group (64 blocks).
// Each block release-stores its epoch to its own 128B-strided slot (no RMW
// contention); wave 0 polls all 64 flags in parallel (one lane per flag).
__device__ __forceinline__ void bg_barrier(unsigned* fbase, int ug, unsigned step, int tid) {
  __syncthreads();
  if (tid == 0) {
    __threadfence();
    __hip_atomic_store(&fbase[ug * 32], step, __ATOMIC_RELEASE, __HIP_MEMORY_SCOPE_AGENT);
  }
  if (tid < 64) {
    unsigned* f = &fbase[tid * 32];
    unsigned v;
    do {
      v = __hip_atomic_load(f, __ATOMIC_RELAXED, __HIP_MEMORY_SCOPE_AGENT);
    } while (__any((int)(v < step)));
    v = __hip_atomic_load(f, __ATOMIC_ACQUIRE, __HIP_MEMORY_SCOPE_AGENT);
    (void)v;
  }
  __syncthreads();
}

// ---------------- generic f32 GEMM: C[M,N] = A[rows][K] @ B[K,N] (+bias) ----------------
__global__ __launch_bounds__(256) void gemm_f32(
    const float* __restrict__ A, const int* __restrict__ Arows, int lda,
    const float* __restrict__ Bm, int ldb, const float* __restrict__ bias,
    float* __restrict__ C, int N, int K)
{
  __shared__ __align__(16) float As[16][68];
  __shared__ __align__(16) float Bs[16][68];
  const int tid = threadIdx.x;
  const int bm = blockIdx.y, bn = blockIdx.x;
  const int tx = tid & 15, ty = tid >> 4;
  float acc[4][4] = {{0.f}};
  const int sm = tid >> 2, sk = (tid & 3) * 4;
  const int arow = Arows ? Arows[bm * 64 + sm] : (bm * 64 + sm);
  const float* Ap = A + (size_t)arow * lda + sk;
  const int bk = tid >> 4, bn4 = (tid & 15) * 4;
  const float* Bp = Bm + (size_t)bk * ldb + bn * 64 + bn4;
  for (int kk = 0; kk < K; kk += 16) {
    float4 av = *(const float4*)(Ap + kk);
    float4 bv = *(const float4*)(Bp + (size_t)kk * ldb);
    As[sk + 0][sm] = av.x; As[sk + 1][sm] = av.y;
    As[sk + 2][sm] = av.z; As[sk + 3][sm] = av.w;
    *(float4*)&Bs[bk][bn4] = bv;
    __syncthreads();
#pragma unroll
    for (int kt = 0; kt < 16; ++kt) {
      float4 a = *(const float4*)&As[kt][ty * 4];
      float4 b = *(const float4*)&Bs[kt][tx * 4];
      acc[0][0] += a.x * b.x; acc[0][1] += a.x * b.y; acc[0][2] += a.x * b.z; acc[0][3] += a.x * b.w;
      acc[1][0] += a.y * b.x; acc[1][1] += a.y * b.y; acc[1][2] += a.y * b.z; acc[1][3] += a.y * b.w;
      acc[2][0] += a.z * b.x; acc[2][1] += a.z * b.y; acc[2][2] += a.z * b.z; acc[2][3] += a.z * b.w;
      acc[3][0] += a.w * b.x; acc[3][1] += a.w * b.y; acc[3][2] += a.w * b.z; acc[3][3] += a.w * b.w;
    }
    __syncthreads();
  }
  const int cm = bm * 64 + ty * 4, cn = bn * 64 + tx * 4;
  float bc0 = bias ? bias[cn + 0] : 0.f;
  float bc1 = bias ? bias[cn + 1] : 0.f;
  float bc2 = bias ? bias[cn + 2] : 0.f;
  float bc3 = bias ? bias[cn + 3] : 0.f;
#pragma unroll
  for (int i = 0; i < 4; ++i) {
    float4 o;
    o.x = acc[i][0] + bc0; o.y = acc[i][1] + bc1;
    o.z = acc[i][2] + bc2; o.w = acc[i][3] + bc3;
    *(float4*)&C[(size_t)(cm + i) * N + cn] = o;
  }
}

__global__ void init_kernel(const float* __restrict__ src_h, float* __restrict__ hb0,
                            unsigned* __restrict__ flags) {
  int i = blockIdx.x * blockDim.x + threadIdx.x;
  if (i < 8192) flags[i] = 0u;
  for (int e = i; e < Bz * Uz; e += gridDim.x * blockDim.x) hb0[e] = src_h[e];
}

// ---------------- persistent decoder: 256 blocks x 512 threads, 1 block/CU ----------------
__global__ __launch_bounds__(512, 1) void decoder_persist(
    const float* __restrict__ Wr,        // [512][2048]
    const float* __restrict__ Wgen,      // [1280][512]
    const float* __restrict__ bgen,      // [512]
    const float* __restrict__ enc_c,     // [64][512]
    const float* __restrict__ embW,      // [512][2048]  emb[0:512]@Wk + b
    const float* __restrict__ xg0,       // [2048][2048] emb[target]@Wk + b
    const float* __restrict__ enc_part,  // [2048][512]
    const float* __restrict__ dec0,      // [2048][512]
    const float* __restrict__ decW,      // [512][512]
    float* __restrict__ hb,              // [2][64][512] double-buffered h
    float* __restrict__ hWb,             // [64][512]
    int*   __restrict__ idxbuf,          // [2][2048] double-buffered by iter parity
    unsigned* __restrict__ flags,        // [4][64][32] per-bg arrival flags
    float* __restrict__ out)
{
  __shared__ __align__(16) float Wl[32][516];
  __shared__ __align__(16) float h_l[16][516];
  __shared__ float g_l[32][17];
  __shared__ float red_v[512];
  __shared__ int   red_i[512];

  const int tid = threadIdx.x;
  const int bid = blockIdx.x;
  const int bg = bid >> 6, ug = bid & 63;
  const int b0 = bg * 16, u0 = ug * 8;

  float* out_dec = out;
  float* out_pg  = out + (size_t)NITER * Bz * Tz * Uz;
  float* out_hs  = out + 2 * (size_t)NITER * Bz * Tz * Uz;
  float* out_cs  = out_hs + (size_t)NITER * Bz * Uz;

  unsigned* fbase = flags + bg * 2048;
  unsigned bt_ = 0;

  // stage this block's Wr slice (8 u's x 4 gates, col-major over k) into LDS -- once
  for (int e = tid; e < 32 * 512; e += 512) {
    int k = e >> 5, jj = e & 31;
    Wl[jj][k] = Wr[(size_t)k * G4 + (jj >> 3) * Uz + u0 + (jj & 7)];
  }

  // compute-thread mapping: 512 threads -> (bl 0..15) x (j 0..31)
  const int lane = tid & 63, w = tid >> 6;
  const int bl = lane & 15, jq = lane >> 4;
  const int j  = w * 4 + jq;                    // j = gate*8 + uu
  const int gcol = (j >> 3) * Uz + u0 + (j & 7);
  const int rbase = (b0 + bl) * Tz;

  // pointwise mapping (tid < 128): (bl2 0..15) x (uu2 0..7)
  const int bl2 = tid >> 3, uu2 = tid & 7;
  float c_reg = 0.f;
  if (tid < 128) c_reg = enc_c[(b0 + bl2) * Uz + (u0 + uu2)];
  __syncthreads();

#pragma unroll 1
  for (int s = 0; s < NITER; ++s) {
    const int* idxp = idxbuf + ((s + 1) & 1) * 2048;   // slot(s-1): read this iter
    int*       idxq = idxbuf + (s & 1) * 2048;         // slot(s):   written by argmax

    // prologue: save pre-update state (hb parity 0 untouched until t=1's barrier)
    if (tid < 128) {
      int b = b0 + bl2, u = u0 + uu2;
      float hp = hb[b * Uz + u];
      out_hs[((size_t)s * Bz + b) * Uz + u] = hp;
      out_cs[((size_t)s * Bz + b) * Uz + u] = c_reg;
    }

    // hW = h_pre @ Wgen[512:1024] for this block's (b,jj-range), k split 4 ways
    {
      const int bH = b0 + (ug >> 2);
      const int jjl = tid & 127, kp = tid >> 7;
      const float* hp = hb + bH * Uz + kp * 128;
      const float* wg = Wgen + (size_t)(512 + kp * 128) * Uz + (ug & 3) * 128 + jjl;
      float a2 = 0.f;
#pragma unroll 8
      for (int k = 0; k < 128; ++k) a2 += hp[k] * wg[(size_t)k * Uz];
      red_v[tid] = a2;
      __syncthreads();
      if (tid < 128)
        hWb[bH * Uz + (ug & 3) * 128 + tid] =
            (red_v[tid] + red_v[tid + 128]) + (red_v[tid + 256] + red_v[tid + 384]);
    }
    __syncthreads();

    // ---- 32 LSTM steps ----
#pragma unroll 1
    for (int t = 0; t < Tz; ++t) {
      const float* hread = hb + (t & 1) * (Bz * Uz);
      float* hwrite = hb + ((t & 1) ^ 1) * (Bz * Uz);
      for (int q = tid; q < 2048; q += 512) {          // stage h slice [16][512]
        int sbl = q >> 7, k4 = q & 127;
        float4 v = *(const float4*)(hread + (b0 + sbl) * Uz + k4 * 4);
        *(float4*)&h_l[sbl][k4 * 4] = v;
      }
      float acc;                                       // xg gather (bias baked in)
      if (s == 0) acc = xg0[(size_t)(rbase + t) * G4 + gcol];
      else        acc = embW[(size_t)idxp[rbase + t] * G4 + gcol];
      __syncthreads();
      float a0 = 0.f, a1 = 0.f, a2 = 0.f, a3 = 0.f;
#pragma unroll 8
      for (int k = 0; k < Uz; k += 4) {
        float4 hv = *(const float4*)&h_l[bl][k];
        float4 wv = *(const float4*)&Wl[j][k];
        a0 += hv.x * wv.x; a1 += hv.y * wv.y;
        a2 += hv.z * wv.z; a3 += hv.w * wv.w;
      }
      acc += (a0 + a1) + (a2 + a3);
      g_l[j][bl] = acc;
      __syncthreads();
      if (tid < 128) {
        float gi = g_l[ 0 + uu2][bl2];
        float gf = g_l[ 8 + uu2][bl2];
        float gc = g_l[16 + uu2][bl2];
        float go = g_l[24 + uu2][bl2];
        c_reg = sigf(gf) * c_reg + sigf(gi) * tanhf(gc);
        float hn = sigf(go) * tanhf(c_reg);
        int b = b0 + bl2, u = u0 + uu2;
        hwrite[b * Uz + u] = hn;
        out_dec[(((size_t)s * Bz + b) * Tz + t) * Uz + u] = hn;
      }
      bt_ += 1; bg_barrier(fbase, ug, bt_, tid);
    }

    // ---- p_gen = sigmoid(enc_part + hW + dec_part + bgen)  (reads idx slot s-1) ----
#pragma unroll 1
    for (int i = 0; i < 8; ++i) {
      int f = ug * 4096 + i * 512 + tid;
      int jj = f & 511, btl = f >> 9;
      int b = b0 + (btl >> 5), t = btl & 31;
      int rr = b * Tz + t;
      float dv;
      if (s == 0) dv = dec0[(size_t)rr * Uz + jj];
      else        dv = decW[(size_t)idxp[rr] * Uz + jj];
      float v = enc_part[(size_t)rr * Uz + jj] + hWb[b * Uz + jj] + dv + bgen[jj];
      out_pg[(((size_t)s * Bz + b) * Tz + t) * Uz + jj] = 1.f / (1.f + expf(-v));
    }

    // ---- argmax over U (ties -> lowest index); writes idx slot s ----
#pragma unroll 1
    for (int i = 0; i < 8; ++i) {
      int rl = ug * 8 + i;
      int b = b0 + (rl >> 5), t = rl & 31;
      const float* row = out_dec + (((size_t)s * Bz + b) * Tz + t) * Uz;
      red_v[tid] = row[tid];
      red_i[tid] = tid;
      __syncthreads();
      for (int off = 256; off > 0; off >>= 1) {
        if (tid < off) {
          float v2 = red_v[tid + off], v1 = red_v[tid];
          int i2 = red_i[tid + off], i1 = red_i[tid];
          if (v2 > v1 || (v2 == v1 && i2 < i1)) { red_v[tid] = v2; red_i[tid] = i2; }
        }
        __syncthreads();
      }
      if (tid == 0) idxq[b * Tz + t] = red_i[0];
      __syncthreads();
    }

    bt_ += 1; bg_barrier(fbase, ug, bt_, tid);   // idx slot s + everything visible
  }
}

extern "C" void kernel_launch(void* const* d_in, const int* in_sizes, int n_in,
                              void* d_out, int out_size, void* d_ws, size_t ws_size,
                              hipStream_t stream) {
  const int*   target = (const int*)d_in[1];
  const float* enc    = (const float*)d_in[2];
  const float* enc_h  = (const float*)d_in[3];
  const float* enc_cp = (const float*)d_in[4];
  const float* emb    = (const float*)d_in[5];
  const float* Wk     = (const float*)d_in[6];
  const float* Wr     = (const float*)d_in[7];
  const float* bb     = (const float*)d_in[8];
  const float* Wgen   = (const float*)d_in[9];
  const float* bgen   = (const float*)d_in[10];
  float* out = (float*)d_out;

  float* ws = (float*)d_ws;
  float* hb       = ws;                         // 2*64*512      = 65536
  float* hWb      = ws + 65536;                 // 64*512        = 32768
  float* embW     = ws + 98304;                 // 512*2048      = 1048576
  float* xg0      = ws + 1146880;               // 2048*2048     = 4194304
  float* enc_part = ws + 5341184;               // 2048*512      = 1048576
  float* dec0     = ws + 6389760;               // 2048*512      = 1048576
  float* decW     = ws + 7438336;               // 512*512       = 262144
  int*   idxbuf   = (int*)(ws + 7700480);       // 2*2048
  unsigned* flags = (unsigned*)(ws + 7704576);  // 4*64*32 = 8192

  init_kernel<<<64, 512, 0, stream>>>(enc_h, hb, flags);
  // embW = emb[0:512] @ Wk + b           M=512  N=2048 K=256
  gemm_f32<<<dim3(32, 8), 256, 0, stream>>>(emb, nullptr, 256, Wk, 2048, bb, embW, 2048, 256);
  // xg0 = emb[target] @ Wk + b           M=2048 N=2048 K=256
  gemm_f32<<<dim3(32, 32), 256, 0, stream>>>(emb, target, 256, Wk, 2048, bb, xg0, 2048, 256);
  // enc_part = enc @ Wgen[0:512]         M=2048 N=512  K=512
  gemm_f32<<<dim3(8, 32), 256, 0, stream>>>(enc, nullptr, 512, Wgen, 512, nullptr, enc_part, 512, 512);
  // dec0 = emb[target] @ Wgen[1024:1280] M=2048 N=512  K=256
  gemm_f32<<<dim3(8, 32), 256, 0, stream>>>(emb, target, 256, Wgen + 1024 * 512, 512, nullptr, dec0, 512, 256);
  // decW = emb[0:512] @ Wgen[1024:1280]  M=512  N=512  K=256
  gemm_f32<<<dim3(8, 8), 256, 0, stream>>>(emb, nullptr, 256, Wgen + 1024 * 512, 512, nullptr, decW, 512, 256);

  decoder_persist<<<256, 512, 0, stream>>>(Wr, Wgen, bgen, enc_cp, embW, xg0,
      enc_part, dec0, decW, hb, hWb, idxbuf, flags, out);
}

// Round 3
// 5486.184 us; speedup vs baseline: 4.3893x; 4.0320x over previous
//
#include <hip/hip_runtime.h>
#include <math.h>

#define Bz 64
#define Tz 32
#define Ez 256
#define Uz 512
#define NITER 31
#define G4 2048
#define NBG 8    // batch groups (8 batches each)
#define NUB 32   // u-blocks per bg (16 u each)
#define BPB 8    // batches per block
#define UPB 16   // u per block
#define JPB 64   // gate-cols per block = 4*UPB

typedef unsigned long long ull;

__device__ __forceinline__ float sigf(float x) { return 1.f / (1.f + expf(-x)); }

#define AT_LOADF(p)    __hip_atomic_load((p), __ATOMIC_RELAXED, __HIP_MEMORY_SCOPE_AGENT)
#define AT_STOREF(p,v) __hip_atomic_store((p), (v), __ATOMIC_RELAXED, __HIP_MEMORY_SCOPE_AGENT)

// Fence-free bg-group barrier: per-block flag lines (64B apart), write-through
// atomics only. __syncthreads drains vmcnt for all waves before s_barrier, so
// the relaxed flag store is ordered after all data stores. Polls are RMWs
// (coherence-point reads, immune to stale per-XCD L2 copies).
__device__ __forceinline__ void bg_barrier(unsigned* fl, int ug, unsigned step, int tid) {
  asm volatile("s_waitcnt vmcnt(0)" ::: "memory");
  __syncthreads();
  if (tid == 0)
    __hip_atomic_store(&fl[ug * 16], step, __ATOMIC_RELAXED, __HIP_MEMORY_SCOPE_AGENT);
  if (tid < NUB) {
    unsigned v;
    do {
      v = __hip_atomic_fetch_add(&fl[tid * 16], 0u, __ATOMIC_RELAXED, __HIP_MEMORY_SCOPE_AGENT);
    } while (v < step);
  }
  __syncthreads();
}

// ---------------- generic f32 GEMM: C[M,N] = A[rows][K] @ B[K,N] (+bias) ----------------
__global__ __launch_bounds__(256) void gemm_f32(
    const float* __restrict__ A, const int* __restrict__ Arows, int lda,
    const float* __restrict__ Bm, int ldb, const float* __restrict__ bias,
    float* __restrict__ C, int N, int K)
{
  __shared__ __align__(16) float As[16][68];
  __shared__ __align__(16) float Bs[16][68];
  const int tid = threadIdx.x;
  const int bm = blockIdx.y, bn = blockIdx.x;
  const int tx = tid & 15, ty = tid >> 4;
  float acc[4][4] = {{0.f}};
  const int sm = tid >> 2, sk = (tid & 3) * 4;
  const int arow = Arows ? Arows[bm * 64 + sm] : (bm * 64 + sm);
  const float* Ap = A + (size_t)arow * lda + sk;
  const int bk = tid >> 4, bn4 = (tid & 15) * 4;
  const float* Bp = Bm + (size_t)bk * ldb + bn * 64 + bn4;
  for (int kk = 0; kk < K; kk += 16) {
    float4 av = *(const float4*)(Ap + kk);
    float4 bv = *(const float4*)(Bp + (size_t)kk * ldb);
    As[sk + 0][sm] = av.x; As[sk + 1][sm] = av.y;
    As[sk + 2][sm] = av.z; As[sk + 3][sm] = av.w;
    *(float4*)&Bs[bk][bn4] = bv;
    __syncthreads();
#pragma unroll
    for (int kt = 0; kt < 16; ++kt) {
      float4 a = *(const float4*)&As[kt][ty * 4];
      float4 b = *(const float4*)&Bs[kt][tx * 4];
      acc[0][0] += a.x * b.x; acc[0][1] += a.x * b.y; acc[0][2] += a.x * b.z; acc[0][3] += a.x * b.w;
      acc[1][0] += a.y * b.x; acc[1][1] += a.y * b.y; acc[1][2] += a.y * b.z; acc[1][3] += a.y * b.w;
      acc[2][0] += a.z * b.x; acc[2][1] += a.z * b.y; acc[2][2] += a.z * b.z; acc[2][3] += a.z * b.w;
      acc[3][0] += a.w * b.x; acc[3][1] += a.w * b.y; acc[3][2] += a.w * b.z; acc[3][3] += a.w * b.w;
    }
    __syncthreads();
  }
  const int cm = bm * 64 + ty * 4, cn = bn * 64 + tx * 4;
  float bc0 = bias ? bias[cn + 0] : 0.f;
  float bc1 = bias ? bias[cn + 1] : 0.f;
  float bc2 = bias ? bias[cn + 2] : 0.f;
  float bc3 = bias ? bias[cn + 3] : 0.f;
#pragma unroll
  for (int i = 0; i < 4; ++i) {
    float4 o;
    o.x = acc[i][0] + bc0; o.y = acc[i][1] + bc1;
    o.z = acc[i][2] + bc2; o.w = acc[i][3] + bc3;
    *(float4*)&C[(size_t)(cm + i) * N + cn] = o;
  }
}

// hbT[bg][parity][u][b_local]; flags zeroed
__global__ void init_kernel(const float* __restrict__ enc_h, float* __restrict__ hbT,
                            unsigned* __restrict__ flags) {
  int i = blockIdx.x * blockDim.x + threadIdx.x;
  if (i < NBG * NUB * 16) flags[i] = 0u;
  if (i < Bz * Uz) {
    int u = i & 511, bb = i >> 9;
    int bg = bb >> 3, b = bb & 7;
    hbT[bg * 8192 + u * 8 + b] = enc_h[(size_t)bb * Uz + u];
  }
}

// ---------------- persistent decoder: 256 blocks x 512 threads, 1 block/CU ----------------
__global__ __launch_bounds__(512, 1) void decoder_persist(
    const float* __restrict__ Wr,        // [512][2048]
    const float* __restrict__ Wgen,      // [1280][512]
    const float* __restrict__ bgen,      // [512]
    const float* __restrict__ enc_h,     // [64][512]
    const float* __restrict__ enc_c,     // [64][512]
    const float* __restrict__ embW,      // [512][2048]  emb[0:512]@Wk + b
    const float* __restrict__ xg0,       // [2048][2048] emb[target]@Wk + b
    const float* __restrict__ enc_part,  // [2048][512]
    const float* __restrict__ dec0,      // [2048][512]
    const float* __restrict__ decW,      // [512][512]
    float* __restrict__ hbT,             // [8][2][512][8] write-through h state
    int*   __restrict__ idxbuf,          // [2][2048]
    unsigned* __restrict__ flags,        // [8][32][16]
    float* __restrict__ out)
{
  __shared__ __align__(16) float WlT[512 * JPB];   // [k][j]  128 KB
  __shared__ __align__(16) float hred[4096];       // h_lT [512][8]  UNION  red [8][32][16]
  __shared__ __align__(16) float g_l[512];         // gates [8 b][64 j] / hW partials
  __shared__ __align__(16) float hW_l[128];        // hW [8 b][16 ul]

  const int tid = threadIdx.x;
  const int bid = blockIdx.x;
  const int bg = bid >> 5, ug = bid & 31;
  const int b0 = bg * BPB, u0 = ug * UPB;
  const int lane = tid & 63, wv_ = tid >> 6;

  float* out_dec = out;
  float* out_pg  = out + (size_t)NITER * Bz * Tz * Uz;
  float* out_hs  = out + 2 * (size_t)NITER * Bz * Tz * Uz;
  float* out_cs  = out_hs + (size_t)NITER * Bz * Uz;

  unsigned* fl = flags + bg * NUB * 16;
  unsigned bt_ = 0;

  // ---- stage Wr slice into LDS transposed: WlT[k][j], j = gate*16+ul ----
  for (int q = 0; q < 64; ++q) {
    int e = q * 512 + tid;
    int k = e >> 6, j = e & 63;
    WlT[k * 64 + j] = Wr[(size_t)k * G4 + (j >> 4) * Uz + u0 + (j & 15)];
  }

  // GEMM mapping: tid = kgrp*32 + tile
  const int kgrp = tid >> 5, tile = tid & 31;
  const int g_bt = tile >> 4, g_jt = tile & 15;
  // out-thread mapping: tile t_t = tid>>4, elem e = tid&15
  const int t_t = tid >> 4, o_e = tid & 15;
  const int o_bl = (t_t >> 4) * 4 + (o_e >> 2);
  const int o_j  = (t_t & 15) * 4 + (o_e & 3);
  const int o_gcol = (o_j >> 4) * Uz + u0 + (o_j & 15);
  const int o_rbase = (b0 + o_bl) * Tz;
  // pointwise mapping (tid<128): b = tid>>4, ul = tid&15
  const int p_b = tid >> 4, p_ul = tid & 15;

  float c_reg = 0.f, h_reg = 0.f;
  if (tid < 128) {
    c_reg = enc_c[(size_t)(b0 + p_b) * Uz + u0 + p_ul];
    h_reg = enc_h[(size_t)(b0 + p_b) * Uz + u0 + p_ul];
  }
  __syncthreads();

#pragma unroll 1
  for (int s = 0; s < NITER; ++s) {
    const int* idxp = idxbuf + ((s + 1) & 1) * 2048;
    int*       idxq = idxbuf + (s & 1) * 2048;

    // ---- stage h(t=0) from hbT parity 0 (write-through data -> LLC reads) ----
    {
      const ull* src = (const ull*)&hbT[bg * 8192];
      ull* dst = (ull*)hred;
#pragma unroll
      for (int q = 0; q < 2; ++q) {
        int u2 = tid + q * 512;
        ull v0 = __hip_atomic_load(&src[u2 * 2], __ATOMIC_RELAXED, __HIP_MEMORY_SCOPE_AGENT);
        ull v1 = __hip_atomic_load(&src[u2 * 2 + 1], __ATOMIC_RELAXED, __HIP_MEMORY_SCOPE_AGENT);
        dst[u2 * 2] = v0; dst[u2 * 2 + 1] = v1;
      }
    }
    // scan outputs (pre-update state) + xg(t=0) prefetch
    if (tid < 128) {
      out_hs[((size_t)s * Bz + b0 + p_b) * Uz + u0 + p_ul] = h_reg;
      out_cs[((size_t)s * Bz + b0 + p_b) * Uz + u0 + p_ul] = c_reg;
    }
    float gv;
    if (s == 0) gv = xg0[(size_t)o_rbase * G4 + o_gcol];
    else {
      int iv = __hip_atomic_load(&idxp[o_rbase], __ATOMIC_RELAXED, __HIP_MEMORY_SCOPE_AGENT);
      gv = embW[(size_t)iv * G4 + o_gcol];
    }
    __syncthreads();

    // ---- hW = h_pre @ Wgen[512:1024] for this block's (8 b x 16 ul) ----
    {
      const int o = tid & 127, kp = tid >> 7;
      const int b = o >> 4, ul = o & 15;
      float a = 0.f;
#pragma unroll 8
      for (int k = kp * 128; k < kp * 128 + 128; ++k)
        a += hred[k * 8 + b] * Wgen[(size_t)(512 + k) * Uz + u0 + ul];
      g_l[kp * 128 + o] = a;
    }
    __syncthreads();
    if (tid < 128)
      hW_l[tid] = (g_l[tid] + g_l[tid + 128]) + (g_l[tid + 256] + g_l[tid + 384]);
    __syncthreads();

    // ---- p_gen (uses pre-update h via hW_l; dec gather via idx(s-1)) ----
#pragma unroll 1
    for (int i = 0; i < 8; ++i) {
      int o = i * 512 + tid;
      int ul = o & 15, t = (o >> 4) & 31, b = o >> 9;
      int r = (b0 + b) * Tz + t;
      float dv;
      if (s == 0) dv = dec0[(size_t)r * Uz + u0 + ul];
      else {
        int iv = __hip_atomic_load(&idxp[r], __ATOMIC_RELAXED, __HIP_MEMORY_SCOPE_AGENT);
        dv = decW[(size_t)iv * Uz + u0 + ul];
      }
      float v = enc_part[(size_t)r * Uz + u0 + ul] + hW_l[b * 16 + ul] + dv + bgen[u0 + ul];
      out_pg[((size_t)(s * Bz + b0 + b) * Tz + t) * Uz + u0 + ul] = sigf(v);
    }
    __syncthreads();

    // ---- 32 LSTM steps ----
#pragma unroll 1
    for (int t = 0; t < Tz; ++t) {
      // GEMM: g[b][j] = sum_k h[k][b]*W[k][j], 4x4 tiles, 16-way k-split
      float acc[4][4] = {{0.f}};
#pragma unroll 4
      for (int kk = 0; kk < 32; ++kk) {
        int k = kk * 16 + kgrp;
        float4 hv = *(const float4*)&hred[k * 8 + g_bt * 4];
        float4 wv = *(const float4*)&WlT[k * 64 + g_jt * 4];
        acc[0][0] += hv.x * wv.x; acc[0][1] += hv.x * wv.y; acc[0][2] += hv.x * wv.z; acc[0][3] += hv.x * wv.w;
        acc[1][0] += hv.y * wv.x; acc[1][1] += hv.y * wv.y; acc[1][2] += hv.y * wv.z; acc[1][3] += hv.y * wv.w;
        acc[2][0] += hv.z * wv.x; acc[2][1] += hv.z * wv.y; acc[2][2] += hv.z * wv.z; acc[2][3] += hv.z * wv.w;
        acc[3][0] += hv.w * wv.x; acc[3][1] += hv.w * wv.y; acc[3][2] += hv.w * wv.z; acc[3][3] += hv.w * wv.w;
      }
#pragma unroll
      for (int bi = 0; bi < 4; ++bi)
#pragma unroll
        for (int ji = 0; ji < 4; ++ji)
          acc[bi][ji] += __shfl_xor(acc[bi][ji], 32);
      __syncthreads();                       // (A) h reads done
      if (lane < 32) {
#pragma unroll
        for (int bi = 0; bi < 4; ++bi) {
          float4 o4; o4.x = acc[bi][0]; o4.y = acc[bi][1]; o4.z = acc[bi][2]; o4.w = acc[bi][3];
          *(float4*)&hred[wv_ * 512 + tile * 16 + bi * 4] = o4;  // red[w][tile][e]
        }
      }
      __syncthreads();                       // (B)
      {
        float gsum = gv;
#pragma unroll
        for (int w = 0; w < 8; ++w) gsum += hred[w * 512 + t_t * 16 + o_e];
        g_l[o_bl * 64 + o_j] = gsum;
      }
      __syncthreads();                       // (C)
      if (tid < 128) {
        float gi = g_l[p_b * 64 +  0 + p_ul];
        float gf = g_l[p_b * 64 + 16 + p_ul];
        float gc = g_l[p_b * 64 + 32 + p_ul];
        float go = g_l[p_b * 64 + 48 + p_ul];
        c_reg = sigf(gf) * c_reg + sigf(gi) * tanhf(gc);
        float hn = sigf(go) * tanhf(c_reg);
        h_reg = hn;
        AT_STOREF(&hbT[bg * 8192 + ((t & 1) ^ 1) * 4096 + (u0 + p_ul) * 8 + p_b], hn);
        AT_STOREF(&out_dec[((size_t)(s * Bz + b0 + p_b) * Tz + t) * Uz + u0 + p_ul], hn);
      }
      bt_ += 1; bg_barrier(fl, ug, bt_, tid);
      if (t < Tz - 1) {
        const ull* src = (const ull*)&hbT[bg * 8192 + ((t & 1) ^ 1) * 4096];
        ull* dst = (ull*)hred;
#pragma unroll
        for (int q = 0; q < 2; ++q) {
          int u2 = tid + q * 512;
          ull v0 = __hip_atomic_load(&src[u2 * 2], __ATOMIC_RELAXED, __HIP_MEMORY_SCOPE_AGENT);
          ull v1 = __hip_atomic_load(&src[u2 * 2 + 1], __ATOMIC_RELAXED, __HIP_MEMORY_SCOPE_AGENT);
          dst[u2 * 2] = v0; dst[u2 * 2 + 1] = v1;
        }
        int r = o_rbase + t + 1;
        if (s == 0) gv = xg0[(size_t)r * G4 + o_gcol];
        else {
          int iv = __hip_atomic_load(&idxp[r], __ATOMIC_RELAXED, __HIP_MEMORY_SCOPE_AGENT);
          gv = embW[(size_t)iv * G4 + o_gcol];
        }
        __syncthreads();                     // (D) h_lT(t+1) ready
      }
    }

    // ---- argmax (ties -> lowest index) over this block's 8 rows ----
    {
      int i = tid >> 6;
      int R = ug * 8 + i;
      int b = R >> 5, t = R & 31;
      const float* row = &out_dec[((size_t)(s * Bz + b0 + b) * Tz + t) * Uz];
      float bv = -3.4e38f; int bi_ = 0;
#pragma unroll
      for (int q = 0; q < 8; ++q) {
        int u = lane + q * 64;
        float v = AT_LOADF(&row[u]);
        if (v > bv) { bv = v; bi_ = u; }
      }
#pragma unroll
      for (int off = 1; off < 64; off <<= 1) {
        float ov = __shfl_xor(bv, off);
        int   oi = __shfl_xor(bi_, off);
        if (ov > bv || (ov == bv && oi < bi_)) { bv = ov; bi_ = oi; }
      }
      if (lane == 0)
        __hip_atomic_store(&idxq[(b0 + b) * Tz + t], bi_, __ATOMIC_RELAXED, __HIP_MEMORY_SCOPE_AGENT);
    }
    bt_ += 1; bg_barrier(fl, ug, bt_, tid);
  }
}

extern "C" void kernel_launch(void* const* d_in, const int* in_sizes, int n_in,
                              void* d_out, int out_size, void* d_ws, size_t ws_size,
                              hipStream_t stream) {
  const int*   target = (const int*)d_in[1];
  const float* enc    = (const float*)d_in[2];
  const float* enc_h  = (const float*)d_in[3];
  const float* enc_cp = (const float*)d_in[4];
  const float* emb    = (const float*)d_in[5];
  const float* Wk     = (const float*)d_in[6];
  const float* Wr     = (const float*)d_in[7];
  const float* bb     = (const float*)d_in[8];
  const float* Wgen   = (const float*)d_in[9];
  const float* bgen   = (const float*)d_in[10];
  float* out = (float*)d_out;

  float* ws = (float*)d_ws;
  float* hbT      = ws;                         // 8*2*512*8     = 65536
  float* embW     = ws + 65536;                 // 512*2048      = 1048576
  float* xg0      = ws + 1114112;               // 2048*2048     = 4194304
  float* enc_part = ws + 5308416;               // 2048*512      = 1048576
  float* dec0     = ws + 6356992;               // 2048*512      = 1048576
  float* decW     = ws + 7405568;               // 512*512       = 262144
  int*   idxbuf   = (int*)(ws + 7667712);       // 2*2048
  unsigned* flags = (unsigned*)(ws + 7671808);  // 8*32*16 = 4096

  init_kernel<<<64, 512, 0, stream>>>(enc_h, hbT, flags);
  // embW = emb[0:512] @ Wk + b           M=512  N=2048 K=256
  gemm_f32<<<dim3(32, 8), 256, 0, stream>>>(emb, nullptr, 256, Wk, 2048, bb, embW, 2048, 256);
  // xg0 = emb[target] @ Wk + b           M=2048 N=2048 K=256
  gemm_f32<<<dim3(32, 32), 256, 0, stream>>>(emb, target, 256, Wk, 2048, bb, xg0, 2048, 256);
  // enc_part = enc @ Wgen[0:512]         M=2048 N=512  K=512
  gemm_f32<<<dim3(8, 32), 256, 0, stream>>>(enc, nullptr, 512, Wgen, 512, nullptr, enc_part, 512, 512);
  // dec0 = emb[target] @ Wgen[1024:1280] M=2048 N=512  K=256
  gemm_f32<<<dim3(8, 32), 256, 0, stream>>>(emb, target, 256, Wgen + 1024 * 512, 512, nullptr, dec0, 512, 256);
  // decW = emb[0:512] @ Wgen[1024:1280]  M=512  N=512  K=256
  gemm_f32<<<dim3(8, 8), 256, 0, stream>>>(emb, nullptr, 256, Wgen + 1024 * 512, 512, nullptr, decW, 512, 256);

  decoder_persist<<<256, 512, 0, stream>>>(Wr, Wgen, bgen, enc_h, enc_cp, embW, xg0,
      enc_part, dec0, decW, hbT, idxbuf, flags, out);
}